// Round 6
// baseline (222.733 us; speedup 1.0000x reference)
//
#include <hip/hip_runtime.h>
#include <hip/hip_bf16.h>
#include <math.h>

#define EPSF 1e-8f

typedef __attribute__((ext_vector_type(8))) short bf16x8;
typedef __attribute__((ext_vector_type(4))) float f32x4;

static __device__ __forceinline__ unsigned short f2bf(float f) {
    __hip_bfloat16 h = __float2bfloat16(f);
    return *reinterpret_cast<unsigned short*>(&h);
}
static __device__ __forceinline__ float bf2f(unsigned short u) {
    __hip_bfloat16 h;
    *reinterpret_cast<unsigned short*>(&h) = u;
    return __bfloat162float(h);
}

// async global->LDS, 16B/lane (used only by nca_flash staging).
// Chunked layout: 1KB chunk = 16 rows x 32 bf16; lane l covers row l>>2,
// cols (l&3)*8..+8. Frag ds_read_b128 of a chunk = contiguous 1KB (no conflict).
static __device__ __forceinline__ void async16(void* lds, const void* g) {
    __builtin_amdgcn_global_load_lds(
        (const __attribute__((address_space(1))) unsigned int*)g,
        (__attribute__((address_space(3))) unsigned int*)lds, 16, 0, 0);
}

// ---------------------------------------------------------------------------
// Combined hi/lo bf16 split of [subx; x] -> planes [31024,256]. Zeroes gl/gy.
// ---------------------------------------------------------------------------
__global__ __launch_bounds__(256) void split_combined(
    const float* __restrict__ subx, const float* __restrict__ x,
    unsigned short* __restrict__ H, unsigned short* __restrict__ L,
    float* __restrict__ gl, float* __restrict__ gy, int n4, int nsubrow)
{
    int i = blockIdx.x * 256 + threadIdx.x;
    if (i < 512) {
        float4 z = make_float4(0.f, 0.f, 0.f, 0.f);
        if (i < 256) ((float4*)gl)[i] = z;
        else         ((float4*)gy)[i - 256] = z;
    }
    if (i >= n4) return;
    int row = i >> 6;   // 64 float4 per 256-col row
    float4 v = (row < nsubrow)
        ? ((const float4*)subx)[i]
        : ((const float4*)x)[i - (size_t)nsubrow * 64];
    unsigned short h0 = f2bf(v.x), h1 = f2bf(v.y), h2 = f2bf(v.z), h3 = f2bf(v.w);
    unsigned short l0 = f2bf(v.x - bf2f(h0));
    unsigned short l1 = f2bf(v.y - bf2f(h1));
    unsigned short l2 = f2bf(v.z - bf2f(h2));
    unsigned short l3 = f2bf(v.w - bf2f(h3));
    uint2 hp, lp;
    hp.x = ((unsigned)h1 << 16) | h0;  hp.y = ((unsigned)h3 << 16) | h2;
    lp.x = ((unsigned)l1 << 16) | l0;  lp.y = ((unsigned)l3 << 16) | l2;
    ((uint2*)H)[i] = hp;
    ((uint2*)L)[i] = lp;
}

// ---------------------------------------------------------------------------
// W [K,N] fp32 -> W^T hi/lo bf16 [N,K].
// ---------------------------------------------------------------------------
__global__ __launch_bounds__(256) void tsplit(
    const float* __restrict__ W, unsigned short* __restrict__ HT,
    unsigned short* __restrict__ LT, int kshift, int N, int total)
{
    int idx = blockIdx.x * 256 + threadIdx.x;
    if (idx >= total) return;
    int K = 1 << kshift;
    int n = idx >> kshift, k = idx & (K - 1);
    float w = W[(size_t)k * N + n];
    unsigned short h = f2bf(w);
    HT[idx] = h;
    LT[idx] = f2bf(w - bf2f(h));
}

// ---------------------------------------------------------------------------
// Layer-1: C = relu((Ah+Al)@(Bh+Bl)^T + bias), 3-term split-bf16 MFMA.
// BARRIER-FREE K-loop: A and B fragments both loaded directly from global
// (16B/lane contiguous); B re-reads served by XCD-L2 (swizzle keeps the 4
// n-tiles of each m-tile on one XCD). No LDS, no __syncthreads until the
// epilogue repack. K=256, N=512 fixed -> fully unrolled straight-line
// stream of loads+MFMAs the compiler pipelines with fine-grained vmcnt.
// ---------------------------------------------------------------------------
__global__ __launch_bounds__(256) void gemm_l1(
    const unsigned short* __restrict__ Ah, const unsigned short* __restrict__ Al,
    const unsigned short* __restrict__ BhT, const unsigned short* __restrict__ BlT,
    const float* __restrict__ bias, unsigned short* __restrict__ Cout, int M)
{
    const int K = 256, N = 512;
    __shared__ __align__(16) unsigned short ctile[128 * 136];

    // inverse round-robin: XCD k owns a contiguous newbid range
    const int nb = gridDim.x;
    const int per = nb >> 3, rem = nb & 7;
    const int xcd = blockIdx.x & 7, slot = blockIdx.x >> 3;
    const int newbid = xcd * per + min(xcd, rem) + slot;
    const int m0 = (newbid >> 2) * 128, n0 = (newbid & 3) * 128;

    const int t = threadIdx.x, wave = t >> 6, lane = t & 63;
    const int quad = lane >> 4, lq = lane & 15;
    const int mhalf = wave >> 1, nhalf = wave & 1;

    const unsigned short *pAh[4], *pAl[4], *pBh[4], *pBl[4];
    #pragma unroll
    for (int i = 0; i < 4; ++i) {
        size_t ar = (size_t)min(m0 + mhalf * 64 + i * 16 + lq, M - 1) * K + quad * 8;
        pAh[i] = Ah + ar;
        pAl[i] = Al + ar;
        size_t br = (size_t)(n0 + nhalf * 64 + i * 16 + lq) * K + quad * 8;
        pBh[i] = BhT + br;
        pBl[i] = BlT + br;
    }

    f32x4 acc[4][4];
    #pragma unroll
    for (int i = 0; i < 4; ++i)
        #pragma unroll
        for (int j = 0; j < 4; ++j) acc[i][j] = (f32x4){0.f, 0.f, 0.f, 0.f};

    #pragma unroll
    for (int kc = 0; kc < 8; ++kc) {
        const int k0 = kc * 32;
        bf16x8 fAh[4], fAl[4], fBh[4], fBl[4];
        #pragma unroll
        for (int i = 0; i < 4; ++i) {
            fAh[i] = *(const bf16x8*)(pAh[i] + k0);
            fAl[i] = *(const bf16x8*)(pAl[i] + k0);
            fBh[i] = *(const bf16x8*)(pBh[i] + k0);
            fBl[i] = *(const bf16x8*)(pBl[i] + k0);
        }
        #pragma unroll
        for (int mi = 0; mi < 4; ++mi)
            #pragma unroll
            for (int ni = 0; ni < 4; ++ni) {
                f32x4 a = acc[mi][ni];
                a = __builtin_amdgcn_mfma_f32_16x16x32_bf16(fAh[mi], fBh[ni], a, 0, 0, 0);
                a = __builtin_amdgcn_mfma_f32_16x16x32_bf16(fAh[mi], fBl[ni], a, 0, 0, 0);
                a = __builtin_amdgcn_mfma_f32_16x16x32_bf16(fAl[mi], fBh[ni], a, 0, 0, 0);
                acc[mi][ni] = a;
            }
    }

    // epilogue: bias+relu, round to bf16, repack via LDS for coalesced stores
    float bv[4];
    #pragma unroll
    for (int ni = 0; ni < 4; ++ni) bv[ni] = bias[n0 + nhalf * 64 + ni * 16 + lq];
    #pragma unroll
    for (int mi = 0; mi < 4; ++mi)
        #pragma unroll
        for (int ni = 0; ni < 4; ++ni)
            #pragma unroll
            for (int r = 0; r < 4; ++r) {
                float v = fmaxf(acc[mi][ni][r] + bv[ni], 0.f);
                ctile[(mhalf * 64 + mi * 16 + quad * 4 + r) * 136 +
                      (nhalf * 64 + ni * 16 + lq)] = f2bf(v);
            }
    __syncthreads();
    #pragma unroll
    for (int it = 0; it < 8; ++it) {
        int flat = it * 256 + t;
        int row = flat >> 4, seg = flat & 15;
        if (m0 + row < M) {
            bf16x8 v = *(const bf16x8*)&ctile[row * 136 + seg * 8];
            *(bf16x8*)&Cout[(size_t)(m0 + row) * N + n0 + seg * 8] = v;
        }
    }
}

// ---------------------------------------------------------------------------
// Layer-2: C = relu(A@(Bh+Bl)^T + bias), 2-term split on weights, N=128.
// Same barrier-free structure: A (z1) and W2^T frags direct from global
// (W2 is 256KB total -> L2-resident on every XCD). K=512, 16 k-chunks.
// Epilogue: rounded bf16 rows + squared norms of the rounded values.
// ---------------------------------------------------------------------------
__global__ __launch_bounds__(256) void gemm_l2_norm(
    const unsigned short* __restrict__ A,
    const unsigned short* __restrict__ BhT, const unsigned short* __restrict__ BlT,
    const float* __restrict__ bias, unsigned short* __restrict__ Cout,
    float* __restrict__ nrm, int M)
{
    const int K = 512;
    __shared__ __align__(16) unsigned short ctile[128 * 136];

    const int t = threadIdx.x, wave = t >> 6, lane = t & 63;
    const int quad = lane >> 4, lq = lane & 15;
    const int m0 = blockIdx.x * 128;
    const int mhalf = wave >> 1, nhalf = wave & 1;

    const unsigned short *pA[4], *pBh[4], *pBl[4];
    #pragma unroll
    for (int i = 0; i < 4; ++i) {
        pA[i] = A + (size_t)min(m0 + mhalf * 64 + i * 16 + lq, M - 1) * K + quad * 8;
        size_t br = (size_t)(nhalf * 64 + i * 16 + lq) * K + quad * 8;
        pBh[i] = BhT + br;
        pBl[i] = BlT + br;
    }

    f32x4 acc[4][4];
    #pragma unroll
    for (int i = 0; i < 4; ++i)
        #pragma unroll
        for (int j = 0; j < 4; ++j) acc[i][j] = (f32x4){0.f, 0.f, 0.f, 0.f};

    #pragma unroll 4
    for (int kc = 0; kc < 16; ++kc) {
        const int k0 = kc * 32;
        bf16x8 fA[4], fBh[4], fBl[4];
        #pragma unroll
        for (int i = 0; i < 4; ++i) {
            fA[i]  = *(const bf16x8*)(pA[i] + k0);
            fBh[i] = *(const bf16x8*)(pBh[i] + k0);
            fBl[i] = *(const bf16x8*)(pBl[i] + k0);
        }
        #pragma unroll
        for (int mi = 0; mi < 4; ++mi)
            #pragma unroll
            for (int ni = 0; ni < 4; ++ni) {
                f32x4 a = acc[mi][ni];
                a = __builtin_amdgcn_mfma_f32_16x16x32_bf16(fA[mi], fBh[ni], a, 0, 0, 0);
                a = __builtin_amdgcn_mfma_f32_16x16x32_bf16(fA[mi], fBl[ni], a, 0, 0, 0);
                acc[mi][ni] = a;
            }
    }

    float bv[4];
    #pragma unroll
    for (int ni = 0; ni < 4; ++ni) bv[ni] = bias[nhalf * 64 + ni * 16 + lq];
    #pragma unroll
    for (int mi = 0; mi < 4; ++mi)
        #pragma unroll
        for (int ni = 0; ni < 4; ++ni)
            #pragma unroll
            for (int r = 0; r < 4; ++r) {
                float v = fmaxf(acc[mi][ni][r] + bv[ni], 0.f);
                ctile[(mhalf * 64 + mi * 16 + quad * 4 + r) * 136 +
                      (nhalf * 64 + ni * 16 + lq)] = f2bf(v);
            }
    __syncthreads();

    int row = t >> 1, half = t & 1;
    float s = 0.f;
    if (m0 + row < M) {
        #pragma unroll
        for (int seg = 0; seg < 8; ++seg) {
            bf16x8 v = *(const bf16x8*)&ctile[row * 136 + half * 64 + seg * 8];
            #pragma unroll
            for (int e = 0; e < 8; ++e) {
                float f = bf2f((unsigned short)v[e]);
                s = fmaf(f, f, s);
            }
            *(bf16x8*)&Cout[(size_t)(m0 + row) * 128 + half * 64 + seg * 8] = v;
        }
    }
    s += __shfl_down(s, 1);
    if (half == 0 && m0 + row < M) nrm[m0 + row] = s;
}

// ---------------------------------------------------------------------------
// Flash NCA, bf16 MFMA pairwise dots. 128-wide j-chunks (half the barriers
// of R5; 32 MFMA per wave per barrier-pair). Per-lane j-order identical to
// the 64-chunk version -> bit-identical accumulation.
// emb = combined embeddings [31024][128]: rows 0..N-1 = sh, N.. = h.
// ---------------------------------------------------------------------------
__global__ __launch_bounds__(256) void nca_flash_mfma(
    const unsigned short* __restrict__ emb, const float* __restrict__ nrm,
    const float* __restrict__ y, float* __restrict__ gl, float* __restrict__ gy,
    int N, int jspan)
{
    __shared__ __align__(16) unsigned short hA[8192];   // 64x128 (4 rc x 4 kc chunks)
    __shared__ __align__(16) unsigned short sB[16384];  // 128x128 (8 rc x 4 kc chunks)
    __shared__ float h2s[64], s2s[128], ys[128];

    const int t = threadIdx.x, wave = t >> 6, lane = t & 63;
    const int quad = lane >> 4, lq = lane & 15;
    const int rsub = lane >> 2, kc8 = (lane & 3) * 8;
    const int i0 = blockIdx.x * 64;
    const int j0base = blockIdx.y * jspan;
    const int jend = min(j0base + jspan, N);
    const unsigned short* hb = emb + (size_t)N * 128;

    #pragma unroll
    for (int q = 0; q < 4; ++q)
        async16(hA + (wave * 4 + q) * 512,
                hb + (size_t)(i0 + wave * 16 + rsub) * 128 + q * 32 + kc8);
    if (t < 64) h2s[t] = nrm[N + i0 + t];
    __syncthreads();

    float myh2[4];
    #pragma unroll
    for (int r = 0; r < 4; ++r) myh2[r] = h2s[wave * 16 + quad * 4 + r];

    float lacc[4] = {0.f, 0.f, 0.f, 0.f};
    float yacc[4] = {0.f, 0.f, 0.f, 0.f};

    for (int j0 = j0base; j0 < jend; j0 += 128) {
        __syncthreads();
        // stage 32 chunks (8 rowchunks x 4 kchunks), 8 per wave
        #pragma unroll
        for (int q = 0; q < 8; ++q) {
            int c = wave * 8 + q;          // 0..31
            int rc = c >> 2, kcq = c & 3;
            int jr = min(j0 + rc * 16 + rsub, jend - 1);
            async16(sB + c * 512, emb + (size_t)jr * 128 + kcq * 32 + kc8);
        }
        if (t < 128) {
            int j = j0 + t;
            s2s[t] = (j < jend) ? nrm[j] : 1e30f;   // OOB -> dist huge -> p=0
            ys[t]  = (j < jend) ? y[j] : 0.f;
        }
        __syncthreads();

        f32x4 acc[8];
        #pragma unroll
        for (int jt = 0; jt < 8; ++jt) acc[jt] = (f32x4){0.f, 0.f, 0.f, 0.f};
        #pragma unroll
        for (int kk = 0; kk < 4; ++kk) {
            bf16x8 a = *(const bf16x8*)&hA[(wave * 4 + kk) * 512 + lq * 32 + quad * 8];
            #pragma unroll
            for (int jt = 0; jt < 8; ++jt) {
                bf16x8 b = *(const bf16x8*)&sB[(jt * 4 + kk) * 512 + lq * 32 + quad * 8];
                acc[jt] = __builtin_amdgcn_mfma_f32_16x16x32_bf16(a, b, acc[jt], 0, 0, 0);
            }
        }

        #pragma unroll
        for (int jt = 0; jt < 8; ++jt) {
            int col = jt * 16 + lq;
            float ss = s2s[col];
            float sy = ys[col];
            #pragma unroll
            for (int r = 0; r < 4; ++r) {
                float d2 = myh2[r] + ss - 2.f * acc[jt][r];
                float d  = sqrtf(fmaxf(d2, 0.f) + EPSF);
                float p  = __expf(-d);
                lacc[r] += p;
                yacc[r]  = fmaf(p, sy, yacc[r]);
            }
        }
    }

    #pragma unroll
    for (int r = 0; r < 4; ++r) {
        #pragma unroll
        for (int off = 8; off > 0; off >>= 1) {
            lacc[r] += __shfl_down(lacc[r], off, 16);
            yacc[r] += __shfl_down(yacc[r], off, 16);
        }
    }
    if (lq == 0) {
        int rowl = wave * 16 + quad * 4;
        #pragma unroll
        for (int r = 0; r < 4; ++r) {
            atomicAdd(&gl[i0 + rowl + r], lacc[r]);
            atomicAdd(&gy[i0 + rowl + r], yacc[r]);
        }
    }
}

__global__ __launch_bounds__(256) void finalize_div(
    const float* __restrict__ gl, const float* __restrict__ gy,
    float* __restrict__ out, int B)
{
    int i = blockIdx.x * 256 + threadIdx.x;
    if (i < B) out[i] = gy[i] / gl[i];
}

// ---------------------------------------------------------------------------
extern "C" void kernel_launch(void* const* d_in, const int* in_sizes, int n_in,
                              void* d_out, int out_size, void* d_ws, size_t ws_size,
                              hipStream_t stream)
{
    const float* x    = (const float*)d_in[0];  // [1024,256]
    const float* subx = (const float*)d_in[1];  // [30000,256]
    const float* suby = (const float*)d_in[2];  // [30000]
    const float* W1   = (const float*)d_in[3];  // [256,512]
    const float* b1   = (const float*)d_in[4];  // [512]
    const float* W2   = (const float*)d_in[5];  // [512,128]
    const float* b2   = (const float*)d_in[6];  // [128]
    float* out = (float*)d_out;                 // [1024]

    const int B = 1024, N = 30000, D = 256, H1 = 512, H2 = 128;
    const int M = N + B;  // 31024 combined rows

    char* wsb = (char*)d_ws;
    size_t off = 0;
    auto alloc = [&](size_t bytes) -> char* {
        char* p = wsb + off;
        off += (bytes + 255) & ~(size_t)255;
        return p;
    };
    unsigned short* cxh  = (unsigned short*)alloc((size_t)M * D * 2);    // 15.9 MB
    unsigned short* cxl  = (unsigned short*)alloc((size_t)M * D * 2);
    unsigned short* w1hT = (unsigned short*)alloc((size_t)H1 * D * 2);
    unsigned short* w1lT = (unsigned short*)alloc((size_t)H1 * D * 2);
    unsigned short* w2hT = (unsigned short*)alloc((size_t)H2 * H1 * 2);
    unsigned short* w2lT = (unsigned short*)alloc((size_t)H2 * H1 * 2);
    unsigned short* z1   = (unsigned short*)alloc((size_t)M * H1 * 2);   // 31.8 MB
    unsigned short* emb  = (unsigned short*)alloc((size_t)M * H2 * 2);   // 7.9 MB
    float* nrm = (float*)alloc((size_t)M * 4);
    float* gl  = (float*)alloc((size_t)B * 4);
    float* gy  = (float*)alloc((size_t)B * 4);
    (void)ws_size; (void)in_sizes; (void)n_in; (void)out_size;

    dim3 blk(256);
    // prep: combined split (+ gl/gy zeroing), weight transpose-splits
    split_combined<<<dim3(M * D / 4 / 256), blk, 0, stream>>>(
        subx, x, cxh, cxl, gl, gy, M * D / 4, N);
    tsplit<<<dim3(D * H1 / 256), blk, 0, stream>>>(W1, w1hT, w1lT, 8, H1, D * H1);
    tsplit<<<dim3(H1 * H2 / 256), blk, 0, stream>>>(W2, w2hT, w2lT, 9, H2, H1 * H2);
    // layer 1 (3-term), barrier-free, XCD-swizzled 1D grid: 243 m x 4 n
    gemm_l1<<<dim3(((M + 127) / 128) * (H1 / 128)), blk, 0, stream>>>(
        cxh, cxl, w1hT, w1lT, b1, z1, M);
    // layer 2 (2-term) + rounded-row norms, barrier-free
    gemm_l2_norm<<<dim3((M + 127) / 128), blk, 0, stream>>>(
        z1, w2hT, w2lT, b2, emb, nrm, M);
    // pairwise + softmax-weighted sum
    const int JSPAN = 512;
    const int NSPLIT = (N + JSPAN - 1) / JSPAN;  // 59
    nca_flash_mfma<<<dim3(B / 64, NSPLIT), blk, 0, stream>>>(
        emb, nrm, suby, gl, gy, N, JSPAN);
    finalize_div<<<dim3(B / 256), blk, 0, stream>>>(gl, gy, out, B);
}

// Round 7
// 184.355 us; speedup vs baseline: 1.2082x; 1.2082x over previous
//
#include <hip/hip_runtime.h>
#include <hip/hip_bf16.h>
#include <math.h>

#define EPSF 1e-8f

typedef __attribute__((ext_vector_type(8))) short bf16x8;
typedef __attribute__((ext_vector_type(4))) float f32x4;

static __device__ __forceinline__ unsigned short f2bf(float f) {
    __hip_bfloat16 h = __float2bfloat16(f);
    return *reinterpret_cast<unsigned short*>(&h);
}
static __device__ __forceinline__ float bf2f(unsigned short u) {
    __hip_bfloat16 h;
    *reinterpret_cast<unsigned short*>(&h) = u;
    return __bfloat162float(h);
}

// async global->LDS, 16B/lane. Chunked layout: 1KB chunk = 16 rows x 32 bf16;
// lane l covers row l>>2, cols (l&3)*8..+8. Frag ds_read_b128 of a chunk is a
// contiguous 1KB wave access (conflict-free).
static __device__ __forceinline__ void async16(void* lds, const void* g) {
    __builtin_amdgcn_global_load_lds(
        (const __attribute__((address_space(1))) unsigned int*)g,
        (__attribute__((address_space(3))) unsigned int*)lds, 16, 0, 0);
}

// ---------------------------------------------------------------------------
// Combined hi/lo bf16 split of [subx; x] -> planes [31024,256].
// Zeroes gl/gy and nrm (nrm is atomically accumulated by gemm_l2).
// ---------------------------------------------------------------------------
__global__ __launch_bounds__(256) void split_combined(
    const float* __restrict__ subx, const float* __restrict__ x,
    unsigned short* __restrict__ H, unsigned short* __restrict__ L,
    float* __restrict__ gl, float* __restrict__ gy, float* __restrict__ nrm,
    int n4, int nsubrow, int nrm4)
{
    int i = blockIdx.x * 256 + threadIdx.x;
    float4 z = make_float4(0.f, 0.f, 0.f, 0.f);
    if (i < 512) {
        if (i < 256) ((float4*)gl)[i] = z;
        else         ((float4*)gy)[i - 256] = z;
    }
    if (i < nrm4) ((float4*)nrm)[i] = z;
    if (i >= n4) return;
    int row = i >> 6;   // 64 float4 per 256-col row
    float4 v = (row < nsubrow)
        ? ((const float4*)subx)[i]
        : ((const float4*)x)[i - (size_t)nsubrow * 64];
    unsigned short h0 = f2bf(v.x), h1 = f2bf(v.y), h2 = f2bf(v.z), h3 = f2bf(v.w);
    unsigned short l0 = f2bf(v.x - bf2f(h0));
    unsigned short l1 = f2bf(v.y - bf2f(h1));
    unsigned short l2 = f2bf(v.z - bf2f(h2));
    unsigned short l3 = f2bf(v.w - bf2f(h3));
    uint2 hp, lp;
    hp.x = ((unsigned)h1 << 16) | h0;  hp.y = ((unsigned)h3 << 16) | h2;
    lp.x = ((unsigned)l1 << 16) | l0;  lp.y = ((unsigned)l3 << 16) | l2;
    ((uint2*)H)[i] = hp;
    ((uint2*)L)[i] = lp;
}

// ---------------------------------------------------------------------------
// W [K,N] fp32 -> W^T hi/lo bf16 [N,K].
// ---------------------------------------------------------------------------
__global__ __launch_bounds__(256) void tsplit(
    const float* __restrict__ W, unsigned short* __restrict__ HT,
    unsigned short* __restrict__ LT, int kshift, int N, int total)
{
    int idx = blockIdx.x * 256 + threadIdx.x;
    if (idx >= total) return;
    int K = 1 << kshift;
    int n = idx >> kshift, k = idx & (K - 1);
    float w = W[(size_t)k * N + n];
    unsigned short h = f2bf(w);
    HT[idx] = h;
    LT[idx] = f2bf(w - bf2f(h));
}

// ---------------------------------------------------------------------------
// Layer-1: C = relu((Ah+Al)@(Bh+Bl)^T + bias), 3-term split-bf16 MFMA.
// OCCUPANCY-FIRST shape: 128x64 tile, 256 thr, acc 2x4 (32 AGPR/wave),
// B hi/lo staged in LDS (8KB/iter, shared), A-frags direct from global,
// B-frags STREAMED (8 live VGPRs). LDS 9.2KB total (64-row 2-pass epilogue
// reuses the stage buffer). launch_bounds(256,5) caps regs ~102 -> target
// 5-6 blocks/CU (20-24 waves) vs the ~3-block ceiling of R3-R6.
// ---------------------------------------------------------------------------
__global__ __launch_bounds__(256, 5) void gemm_l1(
    const unsigned short* __restrict__ Ah, const unsigned short* __restrict__ Al,
    const unsigned short* __restrict__ BhT, const unsigned short* __restrict__ BlT,
    const float* __restrict__ bias, unsigned short* __restrict__ Cout, int M)
{
    const int K = 256, N = 512;
    __shared__ __align__(16) unsigned short smem[4608];  // stage 8KB | ctile 64x72
    unsigned short* sBh = smem;          // 4 chunks
    unsigned short* sBl = smem + 2048;   // 4 chunks

    // XCD swizzle: contiguous newbid range per XCD (m-slice + full B in L2)
    const int nb = gridDim.x;
    const int per = nb >> 3, rem = nb & 7;
    const int xcd = blockIdx.x & 7, slot = blockIdx.x >> 3;
    const int newbid = xcd * per + min(xcd, rem) + slot;
    const int m0 = (newbid >> 3) * 128, n0 = (newbid & 7) * 64;

    const int t = threadIdx.x, wave = t >> 6, lane = t & 63;
    const int quad = lane >> 4, lq = lane & 15;
    const int rsub = lane >> 2, kc8 = (lane & 3) * 8;

    // B staging: 8 chunks (4 Bh + 4 Bl), 2 per wave
    const unsigned short* gb[2];
    unsigned short* lb[2];
    #pragma unroll
    for (int q = 0; q < 2; ++q) {
        int c = wave * 2 + q;
        int plane = c >> 2, rc = c & 3;
        gb[q] = (plane ? BlT : BhT) + (size_t)(n0 + rc * 16 + rsub) * K + kc8;
        lb[q] = (plane ? sBl : sBh) + rc * 512;
    }
    // A fragment row bases (direct global frags), rows wave*32 + mi*16
    const unsigned short* pAh[2];
    const unsigned short* pAl[2];
    #pragma unroll
    for (int mi = 0; mi < 2; ++mi) {
        size_t r = (size_t)min(m0 + wave * 32 + mi * 16 + lq, M - 1) * K + quad * 8;
        pAh[mi] = Ah + r;
        pAl[mi] = Al + r;
    }

    f32x4 acc[2][4];
    #pragma unroll
    for (int i = 0; i < 2; ++i)
        #pragma unroll
        for (int j = 0; j < 4; ++j) acc[i][j] = (f32x4){0.f, 0.f, 0.f, 0.f};

    #pragma unroll
    for (int kc = 0; kc < 8; ++kc) {
        const int k0 = kc * 32;
        __syncthreads();
        #pragma unroll
        for (int q = 0; q < 2; ++q) async16(lb[q], gb[q] + k0);
        bf16x8 fAh[2], fAl[2];
        #pragma unroll
        for (int mi = 0; mi < 2; ++mi) {
            fAh[mi] = *(const bf16x8*)(pAh[mi] + k0);
            fAl[mi] = *(const bf16x8*)(pAl[mi] + k0);
        }
        __syncthreads();

        #pragma unroll
        for (int ni = 0; ni < 4; ++ni) {
            int off = ni * 512 + lq * 32 + quad * 8;
            bf16x8 fBh = *(const bf16x8*)&sBh[off];
            bf16x8 fBl = *(const bf16x8*)&sBl[off];
            #pragma unroll
            for (int mi = 0; mi < 2; ++mi) {
                f32x4 a = acc[mi][ni];
                a = __builtin_amdgcn_mfma_f32_16x16x32_bf16(fAh[mi], fBh, a, 0, 0, 0);
                a = __builtin_amdgcn_mfma_f32_16x16x32_bf16(fAh[mi], fBl, a, 0, 0, 0);
                a = __builtin_amdgcn_mfma_f32_16x16x32_bf16(fAl[mi], fBh, a, 0, 0, 0);
                acc[mi][ni] = a;
            }
        }
    }

    // epilogue: 2 passes of 64 rows through a 64x72 ctile (aliases stage)
    unsigned short* ctile = smem;
    float bv[4];
    #pragma unroll
    for (int ni = 0; ni < 4; ++ni) bv[ni] = bias[n0 + ni * 16 + lq];
    #pragma unroll
    for (int p = 0; p < 2; ++p) {
        __syncthreads();
        if ((wave >> 1) == p) {
            int lrow0 = (wave & 1) * 32;
            #pragma unroll
            for (int mi = 0; mi < 2; ++mi)
                #pragma unroll
                for (int ni = 0; ni < 4; ++ni)
                    #pragma unroll
                    for (int r = 0; r < 4; ++r) {
                        float v = fmaxf(acc[mi][ni][r] + bv[ni], 0.f);
                        ctile[(lrow0 + mi * 16 + quad * 4 + r) * 72 + ni * 16 + lq] = f2bf(v);
                    }
        }
        __syncthreads();
        #pragma unroll
        for (int it = 0; it < 2; ++it) {
            int flat = it * 256 + t;
            int row = flat >> 3, seg = flat & 7;
            int gm = m0 + p * 64 + row;
            if (gm < M) {
                bf16x8 v = *(const bf16x8*)&ctile[row * 72 + seg * 8];
                *(bf16x8*)&Cout[(size_t)gm * N + n0 + seg * 8] = v;
            }
        }
    }
}

// ---------------------------------------------------------------------------
// Layer-2: C = relu(A@(Bh+Bl)^T + bias), 2-term split on weights.
// Same occupancy-first shape: 128x64 tile, acc 2x4, W2^T staged, A (z1)
// direct, B-frags streamed. Row-norm partials (64 cols per block) are
// atomicAdd'ed into nrm (zeroed by split_combined).
// ---------------------------------------------------------------------------
__global__ __launch_bounds__(256, 5) void gemm_l2_norm(
    const unsigned short* __restrict__ A,
    const unsigned short* __restrict__ BhT, const unsigned short* __restrict__ BlT,
    const float* __restrict__ bias, unsigned short* __restrict__ Cout,
    float* __restrict__ nrm, int M)
{
    const int K = 512, N = 128;
    __shared__ __align__(16) unsigned short smem[4608];  // stage 8KB | ctile 64x72
    unsigned short* sBh = smem;
    unsigned short* sBl = smem + 2048;

    const int t = threadIdx.x, wave = t >> 6, lane = t & 63;
    const int quad = lane >> 4, lq = lane & 15;
    const int m0 = (blockIdx.x >> 1) * 128, n0 = (blockIdx.x & 1) * 64;
    const int rsub = lane >> 2, kc8 = (lane & 3) * 8;

    const unsigned short* gb[2];
    unsigned short* lb[2];
    #pragma unroll
    for (int q = 0; q < 2; ++q) {
        int c = wave * 2 + q;
        int plane = c >> 2, rc = c & 3;
        gb[q] = (plane ? BlT : BhT) + (size_t)(n0 + rc * 16 + rsub) * K + kc8;
        lb[q] = (plane ? sBl : sBh) + rc * 512;
    }
    const unsigned short* pA[2];
    #pragma unroll
    for (int mi = 0; mi < 2; ++mi)
        pA[mi] = A + (size_t)min(m0 + wave * 32 + mi * 16 + lq, M - 1) * K + quad * 8;

    f32x4 acc[2][4];
    #pragma unroll
    for (int i = 0; i < 2; ++i)
        #pragma unroll
        for (int j = 0; j < 4; ++j) acc[i][j] = (f32x4){0.f, 0.f, 0.f, 0.f};

    #pragma unroll
    for (int kc = 0; kc < 16; ++kc) {
        const int k0 = kc * 32;
        __syncthreads();
        #pragma unroll
        for (int q = 0; q < 2; ++q) async16(lb[q], gb[q] + k0);
        bf16x8 fA[2];
        #pragma unroll
        for (int mi = 0; mi < 2; ++mi) fA[mi] = *(const bf16x8*)(pA[mi] + k0);
        __syncthreads();

        #pragma unroll
        for (int ni = 0; ni < 4; ++ni) {
            int off = ni * 512 + lq * 32 + quad * 8;
            bf16x8 fBh = *(const bf16x8*)&sBh[off];
            bf16x8 fBl = *(const bf16x8*)&sBl[off];
            #pragma unroll
            for (int mi = 0; mi < 2; ++mi) {
                f32x4 a = acc[mi][ni];
                a = __builtin_amdgcn_mfma_f32_16x16x32_bf16(fA[mi], fBh, a, 0, 0, 0);
                a = __builtin_amdgcn_mfma_f32_16x16x32_bf16(fA[mi], fBl, a, 0, 0, 0);
                acc[mi][ni] = a;
            }
        }
    }

    unsigned short* ctile = smem;
    float bv[4];
    #pragma unroll
    for (int ni = 0; ni < 4; ++ni) bv[ni] = bias[n0 + ni * 16 + lq];
    #pragma unroll
    for (int p = 0; p < 2; ++p) {
        __syncthreads();
        if ((wave >> 1) == p) {
            int lrow0 = (wave & 1) * 32;
            #pragma unroll
            for (int mi = 0; mi < 2; ++mi)
                #pragma unroll
                for (int ni = 0; ni < 4; ++ni)
                    #pragma unroll
                    for (int r = 0; r < 4; ++r) {
                        float v = fmaxf(acc[mi][ni][r] + bv[ni], 0.f);
                        ctile[(lrow0 + mi * 16 + quad * 4 + r) * 72 + ni * 16 + lq] = f2bf(v);
                    }
        }
        __syncthreads();
        #pragma unroll
        for (int it = 0; it < 2; ++it) {
            int flat = it * 256 + t;
            int row = flat >> 3, seg = flat & 7;
            int gm = m0 + p * 64 + row;
            if (gm < M) {
                bf16x8 v = *(const bf16x8*)&ctile[row * 72 + seg * 8];
                *(bf16x8*)&Cout[(size_t)gm * N + n0 + seg * 8] = v;
                float s = 0.f;
                #pragma unroll
                for (int e = 0; e < 8; ++e) {
                    float f = bf2f((unsigned short)v[e]);
                    s = fmaf(f, f, s);
                }
                // reduce the 8 segs of this row (lanes 8k..8k+7 share a row)
                s += __shfl_down(s, 4, 8);
                s += __shfl_down(s, 2, 8);
                s += __shfl_down(s, 1, 8);
                if (seg == 0) atomicAdd(&nrm[gm], s);
            }
        }
    }
}

// ---------------------------------------------------------------------------
// Flash NCA, bf16 MFMA pairwise dots, 128-wide j-chunks (unchanged from R6).
// emb = combined embeddings [31024][128]: rows 0..N-1 = sh, N.. = h.
// ---------------------------------------------------------------------------
__global__ __launch_bounds__(256) void nca_flash_mfma(
    const unsigned short* __restrict__ emb, const float* __restrict__ nrm,
    const float* __restrict__ y, float* __restrict__ gl, float* __restrict__ gy,
    int N, int jspan)
{
    __shared__ __align__(16) unsigned short hA[8192];   // 64x128 (4 rc x 4 kc chunks)
    __shared__ __align__(16) unsigned short sB[16384];  // 128x128 (8 rc x 4 kc chunks)
    __shared__ float h2s[64], s2s[128], ys[128];

    const int t = threadIdx.x, wave = t >> 6, lane = t & 63;
    const int quad = lane >> 4, lq = lane & 15;
    const int rsub = lane >> 2, kc8 = (lane & 3) * 8;
    const int i0 = blockIdx.x * 64;
    const int j0base = blockIdx.y * jspan;
    const int jend = min(j0base + jspan, N);
    const unsigned short* hb = emb + (size_t)N * 128;

    #pragma unroll
    for (int q = 0; q < 4; ++q)
        async16(hA + (wave * 4 + q) * 512,
                hb + (size_t)(i0 + wave * 16 + rsub) * 128 + q * 32 + kc8);
    if (t < 64) h2s[t] = nrm[N + i0 + t];
    __syncthreads();

    float myh2[4];
    #pragma unroll
    for (int r = 0; r < 4; ++r) myh2[r] = h2s[wave * 16 + quad * 4 + r];

    float lacc[4] = {0.f, 0.f, 0.f, 0.f};
    float yacc[4] = {0.f, 0.f, 0.f, 0.f};

    for (int j0 = j0base; j0 < jend; j0 += 128) {
        __syncthreads();
        #pragma unroll
        for (int q = 0; q < 8; ++q) {
            int c = wave * 8 + q;
            int rc = c >> 2, kcq = c & 3;
            int jr = min(j0 + rc * 16 + rsub, jend - 1);
            async16(sB + c * 512, emb + (size_t)jr * 128 + kcq * 32 + kc8);
        }
        if (t < 128) {
            int j = j0 + t;
            s2s[t] = (j < jend) ? nrm[j] : 1e30f;   // OOB -> dist huge -> p=0
            ys[t]  = (j < jend) ? y[j] : 0.f;
        }
        __syncthreads();

        f32x4 acc[8];
        #pragma unroll
        for (int jt = 0; jt < 8; ++jt) acc[jt] = (f32x4){0.f, 0.f, 0.f, 0.f};
        #pragma unroll
        for (int kk = 0; kk < 4; ++kk) {
            bf16x8 a = *(const bf16x8*)&hA[(wave * 4 + kk) * 512 + lq * 32 + quad * 8];
            #pragma unroll
            for (int jt = 0; jt < 8; ++jt) {
                bf16x8 b = *(const bf16x8*)&sB[(jt * 4 + kk) * 512 + lq * 32 + quad * 8];
                acc[jt] = __builtin_amdgcn_mfma_f32_16x16x32_bf16(a, b, acc[jt], 0, 0, 0);
            }
        }

        #pragma unroll
        for (int jt = 0; jt < 8; ++jt) {
            int col = jt * 16 + lq;
            float ss = s2s[col];
            float sy = ys[col];
            #pragma unroll
            for (int r = 0; r < 4; ++r) {
                float d2 = myh2[r] + ss - 2.f * acc[jt][r];
                float d  = sqrtf(fmaxf(d2, 0.f) + EPSF);
                float p  = __expf(-d);
                lacc[r] += p;
                yacc[r]  = fmaf(p, sy, yacc[r]);
            }
        }
    }

    #pragma unroll
    for (int r = 0; r < 4; ++r) {
        #pragma unroll
        for (int off = 8; off > 0; off >>= 1) {
            lacc[r] += __shfl_down(lacc[r], off, 16);
            yacc[r] += __shfl_down(yacc[r], off, 16);
        }
    }
    if (lq == 0) {
        int rowl = wave * 16 + quad * 4;
        #pragma unroll
        for (int r = 0; r < 4; ++r) {
            atomicAdd(&gl[i0 + rowl + r], lacc[r]);
            atomicAdd(&gy[i0 + rowl + r], yacc[r]);
        }
    }
}

__global__ __launch_bounds__(256) void finalize_div(
    const float* __restrict__ gl, const float* __restrict__ gy,
    float* __restrict__ out, int B)
{
    int i = blockIdx.x * 256 + threadIdx.x;
    if (i < B) out[i] = gy[i] / gl[i];
}

// ---------------------------------------------------------------------------
extern "C" void kernel_launch(void* const* d_in, const int* in_sizes, int n_in,
                              void* d_out, int out_size, void* d_ws, size_t ws_size,
                              hipStream_t stream)
{
    const float* x    = (const float*)d_in[0];  // [1024,256]
    const float* subx = (const float*)d_in[1];  // [30000,256]
    const float* suby = (const float*)d_in[2];  // [30000]
    const float* W1   = (const float*)d_in[3];  // [256,512]
    const float* b1   = (const float*)d_in[4];  // [512]
    const float* W2   = (const float*)d_in[5];  // [512,128]
    const float* b2   = (const float*)d_in[6];  // [128]
    float* out = (float*)d_out;                 // [1024]

    const int B = 1024, N = 30000, D = 256, H1 = 512, H2 = 128;
    const int M = N + B;  // 31024 combined rows

    char* wsb = (char*)d_ws;
    size_t off = 0;
    auto alloc = [&](size_t bytes) -> char* {
        char* p = wsb + off;
        off += (bytes + 255) & ~(size_t)255;
        return p;
    };
    unsigned short* cxh  = (unsigned short*)alloc((size_t)M * D * 2);    // 15.9 MB
    unsigned short* cxl  = (unsigned short*)alloc((size_t)M * D * 2);
    unsigned short* w1hT = (unsigned short*)alloc((size_t)H1 * D * 2);
    unsigned short* w1lT = (unsigned short*)alloc((size_t)H1 * D * 2);
    unsigned short* w2hT = (unsigned short*)alloc((size_t)H2 * H1 * 2);
    unsigned short* w2lT = (unsigned short*)alloc((size_t)H2 * H1 * 2);
    unsigned short* z1   = (unsigned short*)alloc((size_t)M * H1 * 2);   // 31.8 MB
    unsigned short* emb  = (unsigned short*)alloc((size_t)M * H2 * 2);   // 7.9 MB
    float* nrm = (float*)alloc((size_t)M * 4);
    float* gl  = (float*)alloc((size_t)B * 4);
    float* gy  = (float*)alloc((size_t)B * 4);
    (void)ws_size; (void)in_sizes; (void)n_in; (void)out_size;

    dim3 blk(256);
    // prep: combined split (+ gl/gy/nrm zeroing), weight transpose-splits
    split_combined<<<dim3(M * D / 4 / 256), blk, 0, stream>>>(
        subx, x, cxh, cxl, gl, gy, nrm, M * D / 4, N, (M + 3) / 4);
    tsplit<<<dim3(D * H1 / 256), blk, 0, stream>>>(W1, w1hT, w1lT, 8, H1, D * H1);
    tsplit<<<dim3(H1 * H2 / 256), blk, 0, stream>>>(W2, w2hT, w2lT, 9, H2, H1 * H2);
    // layer 1 (3-term), 128x64 tiles, XCD-swizzled: 243 m x 8 n = 1944 blocks
    gemm_l1<<<dim3(((M + 127) / 128) * (H1 / 64)), blk, 0, stream>>>(
        cxh, cxl, w1hT, w1lT, b1, z1, M);
    // layer 2 (2-term) + atomic row norms: 243 m x 2 n = 486 blocks
    gemm_l2_norm<<<dim3(((M + 127) / 128) * (H2 / 64)), blk, 0, stream>>>(
        z1, w2hT, w2lT, b2, emb, nrm, M);
    // pairwise + softmax-weighted sum
    const int JSPAN = 512;
    const int NSPLIT = (N + JSPAN - 1) / JSPAN;  // 59
    nca_flash_mfma<<<dim3(B / 64, NSPLIT), blk, 0, stream>>>(
        emb, nrm, suby, gl, gy, N, JSPAN);
    finalize_div<<<dim3(B / 256), blk, 0, stream>>>(gl, gy, out, B);
}